// Round 8
// baseline (91.605 us; speedup 1.0000x reference)
//
#include <hip/hip_runtime.h>

#define NEG_SLOPE 0.01f
#define LOG2E 1.4426950408889634f

constexpr int N = 8192;
constexpr int D = 64;
constexpr int PB = 32;   // rows per prep block == j-window span packed by that block
constexpr int RB = 32;   // rows per main block
constexpr int NW = 8;    // waves per main block (512 threads)

typedef __bf16 bf16x8 __attribute__((ext_vector_type(8)));
typedef float f32x4 __attribute__((ext_vector_type(4)));

#if __has_builtin(__builtin_amdgcn_exp2f)
#define EXP2(x) __builtin_amdgcn_exp2f(x)
#else
#define EXP2(x) exp2f(x)
#endif

// ---------------- K1: s1/s2 (log2e-scaled) + per-block max + bf16 pack ----------------
// 256 blocks x 256 threads; block bid owns rows [bid*32, bid*32+32) == pack-window bid.
// w1/w2/c are folded with log2e so main can use native v_exp_f32 (2^x).
__global__ __launch_bounds__(256) void gat_prep(
    const float* __restrict__ x, const float* __restrict__ W_,
    const float* __restrict__ b, const float* __restrict__ a,
    float* __restrict__ s1g, float* __restrict__ s2g,
    float* __restrict__ blockmax, bf16x8* __restrict__ xf) {
  __shared__ float w1s[D], w2s[D], cs[2];
  __shared__ float s1loc[PB];

  const int t = threadIdx.x;
  const int bid = blockIdx.x;

  // A1: w1/w2 = log2e * W^T a1/a2 (redundant per block; W is 16KB, L2-hot)
  if (t < 128) {
    const int sel = t >> 6, d = t & 63;
    const float* av = a + sel * D;
    float acc = 0.f;
#pragma unroll
    for (int k = 0; k < D; ++k) acc += W_[k * D + d] * av[k];
    (sel ? w2s : w1s)[d] = acc * LOG2E;
  }
  if (t == 128 || t == 129) {
    const int sel = t - 128;
    float acc = 0.f;
    for (int d = 0; d < D; ++d) acc += b[d] * a[sel * D + d];
    cs[sel] = acc * LOG2E;
  }
  __syncthreads();

  // A2: s1/s2 for 32 rows; 8 threads per row, shfl-reduce within 8-lane groups
  {
    const int r = t >> 3, seg = t & 7;
    const int gi = bid * PB + r;
    const float4 xa = *(const float4*)(x + (size_t)gi * D + seg * 8);
    const float4 xb = *(const float4*)(x + (size_t)gi * D + seg * 8 + 4);
    float p1 = xa.x * w1s[seg * 8 + 0] + xa.y * w1s[seg * 8 + 1] +
               xa.z * w1s[seg * 8 + 2] + xa.w * w1s[seg * 8 + 3] +
               xb.x * w1s[seg * 8 + 4] + xb.y * w1s[seg * 8 + 5] +
               xb.z * w1s[seg * 8 + 6] + xb.w * w1s[seg * 8 + 7];
    float p2 = xa.x * w2s[seg * 8 + 0] + xa.y * w2s[seg * 8 + 1] +
               xa.z * w2s[seg * 8 + 2] + xa.w * w2s[seg * 8 + 3] +
               xb.x * w2s[seg * 8 + 4] + xb.y * w2s[seg * 8 + 5] +
               xb.z * w2s[seg * 8 + 6] + xb.w * w2s[seg * 8 + 7];
#pragma unroll
    for (int off = 4; off; off >>= 1) {
      p1 += __shfl_xor(p1, off, 64);
      p2 += __shfl_xor(p2, off, 64);
    }
    if (seg == 0) {
      const float v1 = p1 + cs[0], v2 = p2 + cs[1];
      s1g[gi] = v1;
      s2g[gi] = v2;
      s1loc[r] = v1;
    }
  }

  // A3: pack window bid into B-frags (x rows L1-hot from A2). Raw x, NOT scaled.
  // xf[gid], gid=(bid<<8)|(dt<<6)|fl holds bf16 x[bid*32+(fl>>4)*8+q][dt*16+(fl&15)]
  {
    const int dt = t >> 6, fl = t & 63;
    const int jb = bid * PB + ((fl >> 4) << 3);
    const int col = dt * 16 + (fl & 15);
    bf16x8 f;
#pragma unroll
    for (int q = 0; q < 8; ++q) f[q] = (__bf16)x[(size_t)(jb + q) * D + col];
    xf[(bid << 8) | (dt << 6) | fl] = f;
  }
  __syncthreads();
  if (t == 0) {
    float m = s1loc[0];
#pragma unroll
    for (int r = 1; r < PB; ++r) m = fmaxf(m, s1loc[r]);
    blockmax[bid] = m;
  }
}

// ---------------- K2: MFMA flash aggregation ----------------
// 256 blocks x 512 threads (8 waves -> 2 waves/SIMD). Each wave: both 16-row
// A-frags over j-windows c ≡ w (mod 8); 8 MFMA + 2 Z-MFMA (ones B-frag) per
// 4 B-frag loads; register double-buffer so loads never chain into MFMA.
__global__ __launch_bounds__(512, 2) void gat_main(
    const bf16x8* __restrict__ xf, const float* __restrict__ s1g,
    const float* __restrict__ s2g, const float* __restrict__ blockmax,
    float* __restrict__ out) {
  __shared__ float accT[NW][RB][64];  // 64 KB
  __shared__ float zt[NW][RB];
  __shared__ float gms;

  const int t = threadIdx.x;
  const int lane = t & 63;
  const int w = t >> 6;
  const int arow = lane & 15;
  const int grp = lane >> 4;
  const int ibase = blockIdx.x * RB;

  // global max(s1) from blockmax[256] (log2-scaled domain; max commutes)
  if (t < 64) {
    float v = fmaxf(fmaxf(blockmax[lane], blockmax[lane + 64]),
                    fmaxf(blockmax[lane + 128], blockmax[lane + 192]));
#pragma unroll
    for (int off = 32; off; off >>= 1) v = fmaxf(v, __shfl_xor(v, off, 64));
    if (lane == 0) gms = v;
  }
  __syncthreads();
  const float gm = gms;

  const float s2v0 = s2g[ibase + arow];
  const float s2v1 = s2g[ibase + 16 + arow];
  const float tm0 = s2v0 + gm, tm1 = s2v1 + gm;
  const float mneg0 = -fmaxf(tm0, NEG_SLOPE * tm0);  // -m_i (leaky monotone)
  const float mneg1 = -fmaxf(tm1, NEG_SLOPE * tm1);

  f32x4 a00 = {0.f, 0.f, 0.f, 0.f}, a01 = a00, a02 = a00, a03 = a00;
  f32x4 a10 = a00, a11 = a00, a12 = a00, a13 = a00;
  f32x4 az0 = a00, az1 = a00;  // row-sums of P via ones-B MFMA
  bf16x8 ones;
#pragma unroll
  for (int q = 0; q < 8; ++q) ones[q] = (__bf16)1.0f;

  int c = w;
  bf16x8 xb0 = xf[(c << 8) + 0 * 64 + lane];
  bf16x8 xb1 = xf[(c << 8) + 1 * 64 + lane];
  bf16x8 xb2 = xf[(c << 8) + 2 * 64 + lane];
  bf16x8 xb3 = xf[(c << 8) + 3 * 64 + lane];
  float4 sa = *(const float4*)(s1g + c * 32 + grp * 8);
  float4 sb = *(const float4*)(s1g + c * 32 + grp * 8 + 4);

  constexpr int ITERS = N / 32 / NW;  // 32
  for (int i = 0; i < ITERS; ++i) {
    const int cn = (i == ITERS - 1) ? c : c + NW;  // last iter: dummy reload
    bf16x8 nb0 = xf[(cn << 8) + 0 * 64 + lane];
    bf16x8 nb1 = xf[(cn << 8) + 1 * 64 + lane];
    bf16x8 nb2 = xf[(cn << 8) + 2 * 64 + lane];
    bf16x8 nb3 = xf[(cn << 8) + 3 * 64 + lane];
    const float4 na = *(const float4*)(s1g + cn * 32 + grp * 8);
    const float4 nbb = *(const float4*)(s1g + cn * 32 + grp * 8 + 4);

    // P-frags, all in log2 domain: p = 2^(max(t,0.01t) + mneg)
    bf16x8 pa0, pa1;
    {
      const float* sv = &sa.x;
#pragma unroll
      for (int q = 0; q < 4; ++q) {
        const float t0 = s2v0 + sv[q];
        pa0[q] = (__bf16)EXP2(fmaxf(t0, NEG_SLOPE * t0) + mneg0);
        const float t1 = s2v1 + sv[q];
        pa1[q] = (__bf16)EXP2(fmaxf(t1, NEG_SLOPE * t1) + mneg1);
      }
      const float* sw = &sb.x;
#pragma unroll
      for (int q = 0; q < 4; ++q) {
        const float t0 = s2v0 + sw[q];
        pa0[4 + q] = (__bf16)EXP2(fmaxf(t0, NEG_SLOPE * t0) + mneg0);
        const float t1 = s2v1 + sw[q];
        pa1[4 + q] = (__bf16)EXP2(fmaxf(t1, NEG_SLOPE * t1) + mneg1);
      }
    }

    a00 = __builtin_amdgcn_mfma_f32_16x16x32_bf16(pa0, xb0, a00, 0, 0, 0);
    a01 = __builtin_amdgcn_mfma_f32_16x16x32_bf16(pa0, xb1, a01, 0, 0, 0);
    a02 = __builtin_amdgcn_mfma_f32_16x16x32_bf16(pa0, xb2, a02, 0, 0, 0);
    a03 = __builtin_amdgcn_mfma_f32_16x16x32_bf16(pa0, xb3, a03, 0, 0, 0);
    az0 = __builtin_amdgcn_mfma_f32_16x16x32_bf16(pa0, ones, az0, 0, 0, 0);
    a10 = __builtin_amdgcn_mfma_f32_16x16x32_bf16(pa1, xb0, a10, 0, 0, 0);
    a11 = __builtin_amdgcn_mfma_f32_16x16x32_bf16(pa1, xb1, a11, 0, 0, 0);
    a12 = __builtin_amdgcn_mfma_f32_16x16x32_bf16(pa1, xb2, a12, 0, 0, 0);
    a13 = __builtin_amdgcn_mfma_f32_16x16x32_bf16(pa1, xb3, a13, 0, 0, 0);
    az1 = __builtin_amdgcn_mfma_f32_16x16x32_bf16(pa1, ones, az1, 0, 0, 0);

    xb0 = nb0; xb1 = nb1; xb2 = nb2; xb3 = nb3;
    sa = na; sb = nbb;
    c += NW;
  }

  // Z: az holds row-sums replicated across cols; row = grp*4+reg, any col.
  if (arow == 0) {
#pragma unroll
    for (int reg = 0; reg < 4; ++reg) {
      zt[w][grp * 4 + reg] = az0[reg];
      zt[w][16 + grp * 4 + reg] = az1[reg];
    }
  }

  // C/D frags -> LDS: row = grp*4+reg (+16 for frag1), col = dt*16 + arow
#pragma unroll
  for (int reg = 0; reg < 4; ++reg) {
    accT[w][grp * 4 + reg][0 * 16 + arow] = a00[reg];
    accT[w][grp * 4 + reg][1 * 16 + arow] = a01[reg];
    accT[w][grp * 4 + reg][2 * 16 + arow] = a02[reg];
    accT[w][grp * 4 + reg][3 * 16 + arow] = a03[reg];
    accT[w][16 + grp * 4 + reg][0 * 16 + arow] = a10[reg];
    accT[w][16 + grp * 4 + reg][1 * 16 + arow] = a11[reg];
    accT[w][16 + grp * 4 + reg][2 * 16 + arow] = a12[reg];
    accT[w][16 + grp * 4 + reg][3 * 16 + arow] = a13[reg];
  }
  __syncthreads();

#pragma unroll
  for (int k = 0; k < 4; ++k) {
    const int r = w * 4 + k;
    float s = 0.f, z = 0.f;
#pragma unroll
    for (int v = 0; v < NW; ++v) {
      s += accT[v][r][lane];
      z += zt[v][r];
    }
    out[(size_t)(ibase + r) * D + lane] = s / z;
  }
}

extern "C" void kernel_launch(void* const* d_in, const int* in_sizes, int n_in,
                              void* d_out, int out_size, void* d_ws, size_t ws_size,
                              hipStream_t stream) {
  const float* x = (const float*)d_in[0];   // 8192*64 f32
  const float* W = (const float*)d_in[1];   // 64*64
  const float* b = (const float*)d_in[2];   // 64
  const float* a = (const float*)d_in[3];   // 128

  // ws: s1[8192] | s2[8192] | blockmax[256] | @1MB: xf (1MB bf16 frags)
  float* s1 = (float*)d_ws;
  float* s2 = s1 + N;
  float* blockmax = s2 + N;
  bf16x8* xf = (bf16x8*)((char*)d_ws + (1u << 20));
  float* out = (float*)d_out;

  gat_prep<<<N / PB, 256, 0, stream>>>(x, W, b, a, s1, s2, blockmax, xf);
  gat_main<<<N / RB, 512, 0, stream>>>(xf, s1, s2, blockmax, out);
}